// Round 13
// baseline (42.715 us; speedup 1.0000x reference)
//
#include <hip/hip_runtime.h>

// out[b,u] = tanh( exp( max_i x[b,i]*W[i,u] ) - 1 + bias[u] )
// exp monotonic -> max commutes -> max-times "GEMM" + transcendental epilogue.
//
// R13: DUPLICATION PROBE. R7 kernel (best, 26.06us) with grid x2; block pairs
// (2g, 2g+1) do IDENTICAL work and store identical bytes (benign duplicate
// writes; output unchanged). Decodes the 26us plateau into fixed-vs-work:
//   dur ~48-52  -> no fixed floor, plateau = per-work latency (keep attacking)
//   dur ~39     -> ~13us fixed component (kernel is really ~13us)
//   dur ~30-33  -> ~20us fixed floor (R7 is final; environment-bound)

#define BATCH 2048
#define INDIM 512
#define UNITS 512

#define KC 32   // k-chunk per wave
#define RB 16   // rows per block (= rows per group; 1 group)
#define NW 16   // waves per block

typedef float v2f __attribute__((ext_vector_type(2)));

__global__ __launch_bounds__(1024, 8) void maxexp_kernel(
    const float* __restrict__ x,     // [BATCH][INDIM]
    const float* __restrict__ W,     // [INDIM][UNITS]
    const float* __restrict__ bias,  // [UNITS]
    float* __restrict__ out)         // [BATCH][UNITS]
{
    __shared__ float part[RB][NW][64];   // 64 KB

    // duplication: block pairs share f = blockIdx.x >> 1 (identical work)
    const int f   = blockIdx.x >> 1;                   // 0..1023
    const int bg  = (f & 7) * 16 + ((f >> 3) & 15);    // band 0..127
    const int ut  = f >> 7;                            // u-tile 0..7

    const int lane = threadIdx.x & 63;
    const int wv   = __builtin_amdgcn_readfirstlane(threadIdx.x >> 6); // 0..15
    const int u    = ut * 64 + lane;       // unit (per-lane)
    const int k0   = wv * KC;              // k-chunk base (uniform)
    const int b0   = bg * RB;              // first row (uniform)

    // ---- preload W chunk as v2f pairs: (W[k0+2j][u], W[k0+2j+1][u]) ----
    v2f wp[KC / 2];
    {
        const float* wb = W + (size_t)k0 * UNITS + u;
#pragma unroll
        for (int j = 0; j < KC / 2; ++j) {
            v2f t;
            t.x = wb[(size_t)(2 * j)     * UNITS];
            t.y = wb[(size_t)(2 * j + 1) * UNITS];
            wp[j] = t;
        }
    }
#pragma unroll
    for (int j = 0; j < KC / 2; ++j) asm("" : "+v"(wp[j]));  // pin in VGPRs

    const float* xb = x + (size_t)b0 * INDIM + k0;   // uniform base

    float acc[RB];
#pragma unroll
    for (int t = 0; t < RB; ++t) {
        const v2f* xr = reinterpret_cast<const v2f*>(xb + (size_t)t * INDIM);
        float m0 = -3.4e38f, m1 = -3.4e38f;   // two chains
#pragma unroll
        for (int j = 0; j < KC / 2; j += 2) {
            v2f p0, p1;
            // x pair from SGPRs (one 64-bit scalar operand), W pair from VGPRs
            asm("v_pk_mul_f32 %0, %1, %2" : "=v"(p0) : "s"(xr[j]),     "v"(wp[j]));
            asm("v_pk_mul_f32 %0, %1, %2" : "=v"(p1) : "s"(xr[j + 1]), "v"(wp[j + 1]));
            m0 = fmaxf(fmaxf(m0, p0.x), p0.y);   // -> v_max3_f32
            m1 = fmaxf(fmaxf(m1, p1.x), p1.y);
        }
        acc[t] = fmaxf(m0, m1);
    }

    // ---- 16-way cross-wave max combine via LDS (single barrier pair) ----
#pragma unroll
    for (int t = 0; t < RB; ++t) part[t][wv][lane] = acc[t];
    __syncthreads();

    // wave wv reduces + stores row wv
    {
        const int t = wv;
        float m = -3.4e38f;
#pragma unroll
        for (int j = 0; j < NW; j += 2)
            m = fmaxf(fmaxf(m, part[t][j][lane]), part[t][j + 1][lane]);
        const float pp = __expf(m) - 1.0f + bias[u];
        const float e  = __expf(2.0f * pp);
        out[(size_t)(b0 + t) * UNITS + u] = 1.0f - 2.0f / (e + 1.0f);
    }
}

extern "C" void kernel_launch(void* const* d_in, const int* in_sizes, int n_in,
                              void* d_out, int out_size, void* d_ws, size_t ws_size,
                              hipStream_t stream) {
    const float* x    = (const float*)d_in[0];
    const float* W    = (const float*)d_in[1];
    const float* bias = (const float*)d_in[2];
    float* out = (float*)d_out;

    dim3 grid(2 * (BATCH / RB) * (UNITS / 64));  // 2048 blocks: pairs duplicate
    dim3 block(1024);                            // 16 waves
    maxexp_kernel<<<grid, block, 0, stream>>>(x, W, bias, out);
}

// Round 14
// 33.974 us; speedup vs baseline: 1.2573x; 1.2573x over previous
//
#include <hip/hip_runtime.h>
#include <hip/hip_fp16.h>

// out[b,u] = tanh( exp( max_i x[b,i]*W[i,u] ) - 1 + bias[u] )
// exp monotonic -> max commutes -> max-times "GEMM" + transcendental epilogue.
//
// R14: fp16 packed-math main kernel + tiny cvt pre-pass.
// R13 probe: T = 9.4us fixed + 16.7us work for R7; and VGPR_Count=28 < |wp|
// proved the "VGPR-resident W" never materialized in R4-R13 (remat/spill).
// Here: v_pk_mul_f16 (x pair from ONE SGPR) + v_pk_max_f16 (packed acc):
// 1 inst/product, HALF the operand bytes, wp=16 VGPRs (small enough to
// actually stay resident), acc written straight to LDS (no acc array).
//   cvt kernel: x,W f32 -> fp16 pairs in d_ws (coalesced, ~1-2us).
//   main: block = 16 waves x 64 units; wave = 32 k (16 pairs) x 16 rows;
//   16-way k-combine in LDS; wave wv does epilogue+store for row wv.

#define BATCH 2048
#define INDIM 512
#define UNITS 512

#define KP 16    // k-pairs per wave (32 k)
#define RB 16    // rows per block
#define NW 16    // waves per block (NW * 2*KP == INDIM)

#define XPAIRS (BATCH * INDIM / 2)   // 524288
#define WPAIRS (INDIM / 2 * UNITS)   // 131072

__global__ __launch_bounds__(256) void cvt_kernel(
    const float* __restrict__ x, const float* __restrict__ W,
    unsigned int* __restrict__ xh, unsigned int* __restrict__ wph)
{
    const int t = blockIdx.x * 256 + threadIdx.x;
    if (t < XPAIRS) {
        // x fp16 pairs: xh[b*256 + kp] = (x[b][2kp], x[b][2kp+1])
        const float2 v = reinterpret_cast<const float2*>(x)[t];
        xh[t] = (unsigned)__half_as_ushort(__float2half_rn(v.x))
              | ((unsigned)__half_as_ushort(__float2half_rn(v.y)) << 16);
    } else if (t - XPAIRS < WPAIRS) {
        // W fp16 pairs, k-pair major: wph[kp*512 + u] = (W[2kp][u], W[2kp+1][u])
        const int t2 = t - XPAIRS;
        const int kp = t2 >> 9, u = t2 & 511;
        const float a = W[(size_t)(2 * kp) * UNITS + u];
        const float b = W[(size_t)(2 * kp + 1) * UNITS + u];
        wph[t2] = (unsigned)__half_as_ushort(__float2half_rn(a))
                | ((unsigned)__half_as_ushort(__float2half_rn(b)) << 16);
    }
}

__global__ __launch_bounds__(1024, 8) void maxexp_kernel(
    const unsigned int* __restrict__ xh,   // [BATCH][256]  x fp16 pairs
    const unsigned int* __restrict__ wph,  // [256][512]    W fp16 pairs
    const float* __restrict__ bias,        // [UNITS]
    float* __restrict__ out)               // [BATCH][UNITS]
{
    __shared__ unsigned int part[RB][NW][64];   // 64 KB -> 2 blocks/CU

    // bijective XCD swizzle: XCD (f&7) owns 16 contiguous bands x all u-tiles.
    const int f    = blockIdx.x;                       // 0..1023
    const int bg   = (f & 7) * 16 + ((f >> 3) & 15);   // band 0..127
    const int ut   = f >> 7;                           // u-tile 0..7

    const int lane = threadIdx.x & 63;
    const int wv   = __builtin_amdgcn_readfirstlane(threadIdx.x >> 6); // 0..15
    const int u    = ut * 64 + lane;     // unit (per-lane)
    const int kp0  = wv * KP;            // k-pair base (uniform)
    const int b0   = bg * RB;            // first row (uniform)

    // ---- preload W chunk: 16 packed pairs = 16 VGPRs (coalesced dwords) ----
    unsigned int wp[KP];
    {
        const unsigned int* wb = wph + (size_t)kp0 * UNITS + u;
#pragma unroll
        for (int j = 0; j < KP; ++j) wp[j] = wb[(size_t)j * UNITS];
    }
#pragma unroll
    for (int j = 0; j < KP; ++j) asm("" : "+v"(wp[j]));

    const unsigned int* xb = xh + (size_t)b0 * (INDIM / 2) + kp0;  // uniform

    // ---- 16 rows: x pair from ONE SGPR, W pair from VGPR, packed max acc ----
#pragma unroll
    for (int t = 0; t < RB; ++t) {
        const unsigned int* xr = xb + (size_t)t * (INDIM / 2);  // uniform
        unsigned int mA = 0xFC00FC00u, mB = 0xFC00FC00u;  // (-inf,-inf) fp16
#pragma unroll
        for (int j = 0; j < KP; j += 2) {
            unsigned int p0, p1;
            asm("v_pk_mul_f16 %0, %1, %2" : "=v"(p0) : "s"(xr[j]),     "v"(wp[j]));
            asm("v_pk_mul_f16 %0, %1, %2" : "=v"(p1) : "s"(xr[j + 1]), "v"(wp[j + 1]));
            asm("v_pk_max_f16 %0, %0, %1" : "+v"(mA) : "v"(p0));
            asm("v_pk_max_f16 %0, %0, %1" : "+v"(mB) : "v"(p1));
        }
        asm("v_pk_max_f16 %0, %0, %1" : "+v"(mA) : "v"(mB));
        part[t][wv][lane] = mA;   // straight to LDS; no acc array
    }

    __syncthreads();   // all partials ready

    // ---- wave wv: 16-way packed-max combine for row wv, epilogue, store ----
    {
        unsigned int m = part[wv][0][lane];
#pragma unroll
        for (int j = 1; j < NW; ++j) {
            const unsigned int pj = part[wv][j][lane];
            asm("v_pk_max_f16 %0, %0, %1" : "+v"(m) : "v"(pj));
        }
        const float lo = __half2float(__ushort_as_half((unsigned short)(m & 0xffffu)));
        const float hi = __half2float(__ushort_as_half((unsigned short)(m >> 16)));
        const float mm = fmaxf(lo, hi);
        const float pp = __expf(mm) - 1.0f + bias[u];
        const float e  = __expf(2.0f * pp);
        out[(size_t)(b0 + wv) * UNITS + u] = 1.0f - 2.0f / (e + 1.0f);
    }
}

extern "C" void kernel_launch(void* const* d_in, const int* in_sizes, int n_in,
                              void* d_out, int out_size, void* d_ws, size_t ws_size,
                              hipStream_t stream) {
    const float* x    = (const float*)d_in[0];
    const float* W    = (const float*)d_in[1];
    const float* bias = (const float*)d_in[2];
    float* out = (float*)d_out;

    unsigned int* xh  = (unsigned int*)d_ws;            // 2 MB
    unsigned int* wph = xh + XPAIRS;                    // 0.5 MB

    const int cvt_blocks = (XPAIRS + WPAIRS + 255) / 256;   // 2560
    cvt_kernel<<<cvt_blocks, 256, 0, stream>>>(x, W, xh, wph);

    dim3 grid(BATCH / RB * (UNITS / 64));   // 128 bands * 8 u-tiles = 1024
    dim3 block(1024);                       // 16 waves
    maxexp_kernel<<<grid, block, 0, stream>>>(xh, wph, bias, out);
}

// Round 15
// 25.345 us; speedup vs baseline: 1.6853x; 1.3405x over previous
//
#include <hip/hip_runtime.h>

// out[b,u] = tanh( exp( max_i x[b,i]*W[i,u] ) - 1 + bias[u] )
// exp monotonic -> max commutes -> max-times "GEMM" + transcendental epilogue.
//
// R15 = R7 + batched SGPR x-buffers. R13/R14 decomposition: T = 9.4us fixed
// per dispatch + W; R7's W=16.7us vs 6.8us VALU floor. R13's SGPR_Count=48
// proves the compiler issued narrow per-use s_loads with lgkmcnt(0) drains
// (SMEM is out-of-order -> full drain each time): ~250cy stall per ~64cy row.
// Fix: explicitly batch TWO rows' x chunks into named v2f locals (64 SGPRs,
// pinned to SGPR by the "s" asm constraint), sched_barrier between batch-load
// and compute -> 8 s_loads issue together, ONE drain per 128cy of compute.

#define BATCH 2048
#define INDIM 512
#define UNITS 512

#define KC 32   // k-chunk per wave
#define RB 16   // rows per block
#define NW 16   // waves per block (NW*KC == INDIM)

typedef float v2f __attribute__((ext_vector_type(2)));

__global__ __launch_bounds__(1024, 8) void maxexp_kernel(
    const float* __restrict__ x,     // [BATCH][INDIM]
    const float* __restrict__ W,     // [INDIM][UNITS]
    const float* __restrict__ bias,  // [UNITS]
    float* __restrict__ out)         // [BATCH][UNITS]
{
    __shared__ float part[RB][NW][64];   // 64 KB

    // bijective XCD swizzle: XCD (f&7) owns 16 contiguous bands x all u-tiles.
    const int f   = blockIdx.x;                        // 0..1023
    const int bg  = (f & 7) * 16 + ((f >> 3) & 15);    // band 0..127
    const int ut  = f >> 7;                            // u-tile 0..7

    const int lane = threadIdx.x & 63;
    const int wv   = __builtin_amdgcn_readfirstlane(threadIdx.x >> 6); // 0..15
    const int u    = ut * 64 + lane;       // unit (per-lane)
    const int k0   = wv * KC;              // k-chunk base (uniform)
    const int b0   = bg * RB;              // first row (uniform)

    // ---- preload W chunk as v2f pairs ----
    v2f wp[KC / 2];
    {
        const float* wb = W + (size_t)k0 * UNITS + u;
#pragma unroll
        for (int j = 0; j < KC / 2; ++j) {
            v2f t;
            t.x = wb[(size_t)(2 * j)     * UNITS];
            t.y = wb[(size_t)(2 * j + 1) * UNITS];
            wp[j] = t;
        }
    }
#pragma unroll
    for (int j = 0; j < KC / 2; ++j) asm("" : "+v"(wp[j]));

    const v2f* xb = reinterpret_cast<const v2f*>(x + (size_t)b0 * INDIM + k0);
    const int xstr = INDIM / 2;   // v2f elements per row

    float acc[RB];

#pragma unroll
    for (int p = 0; p < RB / 2; ++p) {
        // ---- batch-load 2 rows of x into SGPR buffers (8 s_load_dwordx8) ----
        v2f xa[KC / 2], xc[KC / 2];
#pragma unroll
        for (int j = 0; j < KC / 2; ++j) xa[j] = xb[(size_t)(2 * p) * xstr + j];
#pragma unroll
        for (int j = 0; j < KC / 2; ++j) xc[j] = xb[(size_t)(2 * p + 1) * xstr + j];
        __builtin_amdgcn_sched_barrier(0);   // all loads issued before any use

        // ---- row 2p ----
        {
            float m0 = -3.4e38f, m1 = -3.4e38f;
#pragma unroll
            for (int j = 0; j < KC / 2; j += 2) {
                v2f p0, p1;
                asm("v_pk_mul_f32 %0, %1, %2" : "=v"(p0) : "s"(xa[j]),     "v"(wp[j]));
                asm("v_pk_mul_f32 %0, %1, %2" : "=v"(p1) : "s"(xa[j + 1]), "v"(wp[j + 1]));
                m0 = fmaxf(fmaxf(m0, p0.x), p0.y);   // -> v_max3_f32
                m1 = fmaxf(fmaxf(m1, p1.x), p1.y);
            }
            acc[2 * p] = fmaxf(m0, m1);
        }
        // ---- row 2p+1 ----
        {
            float m0 = -3.4e38f, m1 = -3.4e38f;
#pragma unroll
            for (int j = 0; j < KC / 2; j += 2) {
                v2f p0, p1;
                asm("v_pk_mul_f32 %0, %1, %2" : "=v"(p0) : "s"(xc[j]),     "v"(wp[j]));
                asm("v_pk_mul_f32 %0, %1, %2" : "=v"(p1) : "s"(xc[j + 1]), "v"(wp[j + 1]));
                m0 = fmaxf(fmaxf(m0, p0.x), p0.y);
                m1 = fmaxf(fmaxf(m1, p1.x), p1.y);
            }
            acc[2 * p + 1] = fmaxf(m0, m1);
        }
    }

    // ---- 16-way cross-wave max combine via LDS (single barrier) ----
#pragma unroll
    for (int t = 0; t < RB; ++t) part[t][wv][lane] = acc[t];
    __syncthreads();

    // wave wv reduces + stores row wv
    {
        const int t = wv;
        float m = -3.4e38f;
#pragma unroll
        for (int j = 0; j < NW; j += 2)
            m = fmaxf(fmaxf(m, part[t][j][lane]), part[t][j + 1][lane]);
        const float pp = __expf(m) - 1.0f + bias[u];
        const float e  = __expf(2.0f * pp);
        out[(size_t)(b0 + t) * UNITS + u] = 1.0f - 2.0f / (e + 1.0f);
    }
}

extern "C" void kernel_launch(void* const* d_in, const int* in_sizes, int n_in,
                              void* d_out, int out_size, void* d_ws, size_t ws_size,
                              hipStream_t stream) {
    const float* x    = (const float*)d_in[0];
    const float* W    = (const float*)d_in[1];
    const float* bias = (const float*)d_in[2];
    float* out = (float*)d_out;

    dim3 grid(BATCH / RB * (UNITS / 64));   // 128 bands * 8 u-tiles = 1024
    dim3 block(1024);                       // 16 waves
    maxexp_kernel<<<grid, block, 0, stream>>>(x, W, bias, out);
}